// Round 1
// baseline (89.569 us; speedup 1.0000x reference)
//
#include <hip/hip_runtime.h>
#include <hip/hip_bf16.h>

#define NTHREADS 256

namespace {
constexpr int C = 8;
constexpr int G = 8;
constexpr int M = 256;
constexpr int DEPTH = 9;
constexpr int NPT = 1023;   // nodes per tree
constexpr int NINT = 511;   // internal nodes per tree

__global__ __launch_bounds__(NTHREADS, 2)
void htmm_fused(const float* __restrict__ A, const float* __restrict__ Bm,
                const float* __restrict__ Pi, const int* __restrict__ x,
                float* __restrict__ out)
{
    // beta: upward beliefs, reused in place as eps on the downward pass.
    // tbeta: transition-averaged beliefs, reused in place as w = eps/tbeta.
    __shared__ float beta[NPT][9];          // padded to 9 -> conflict-free strided reads
    __shared__ float tbeta[NINT][9];
    __shared__ __hip_bfloat16 bx[NPT][C];   // gathered emission probs (bf16 to fit 2 wg/CU)
    __shared__ float smA[C][C];
    __shared__ float AlogA[C][C];
    __shared__ float smPi[C];
    __shared__ float logPi[C];
    __shared__ float den[C];
    __shared__ float part[C][32];
    __shared__ float red[NTHREADS / 64];

    const int tid  = threadIdx.x;
    const int tree = blockIdx.x >> 3;
    const int g    = blockIdx.x & 7;

    // ---- phase 1: load raw A, B-row partial sums ----
    if (tid < C * C) {
        int i = tid >> 3, j = tid & 7;
        smA[i][j] = A[(i * C + j) * G + g];     // raw values for now
    }
    {
        int i = tid >> 5, t = tid & 31;         // 32 threads per emission row
        float s = 0.f;
        for (int m = t; m < M; m += 32)
            s += __expf(Bm[(i * M + m) * G + g]);
        part[i][t] = s;
    }
    __syncthreads();

    // ---- phase 2: finalize softmaxes ----
    if (tid < C) {                              // softmax of A over parent dim (axis 0), col j
        int j = tid;
        float mx = -1e30f;
        for (int i = 0; i < C; ++i) mx = fmaxf(mx, smA[i][j]);
        float s = 0.f;
        for (int i = 0; i < C; ++i) s += __expf(smA[i][j] - mx);
        float ls = __logf(s);
        float inv = 1.f / s;
        for (int i = 0; i < C; ++i) {
            float raw = smA[i][j];
            float v = __expf(raw - mx) * inv;
            smA[i][j]  = v;
            AlogA[i][j] = v * (raw - mx - ls);  // smA * log(smA)
        }
    } else if (tid < 2 * C) {                   // emission row denominators
        int i = tid - C;
        float s = 0.f;
        for (int t = 0; t < 32; ++t) s += part[i][t];
        den[i] = s;
    } else if (tid == 2 * C) {                  // Pi softmax
        float raw[C];
        float mx = -1e30f;
        for (int i = 0; i < C; ++i) { raw[i] = Pi[i * G + g]; mx = fmaxf(mx, raw[i]); }
        float s = 0.f;
        for (int i = 0; i < C; ++i) s += __expf(raw[i] - mx);
        float ls = __logf(s);
        float inv = 1.f / s;
        for (int i = 0; i < C; ++i) {
            smPi[i]  = __expf(raw[i] - mx) * inv;
            logPi[i] = raw[i] - mx - ls;
        }
    }
    __syncthreads();

    // ---- phase 3: gather per-node emission probs bx[n][i] = smB[i, x[n]] ----
    for (int n = tid; n < NPT; n += NTHREADS) {
        int xn = x[tree * NPT + n];
        #pragma unroll
        for (int i = 0; i < C; ++i) {
            float v = __expf(Bm[(i * M + xn) * G + g]) / den[i];
            bx[n][i] = __float2bfloat16(v);
        }
    }
    __syncthreads();

    // ---- leaf init: beta[leaf] = normalize(Pi * bx) ----
    for (int n0 = tid; n0 < 512; n0 += NTHREADS) {
        int n = NINT + n0;
        float b[C], s = 0.f;
        #pragma unroll
        for (int i = 0; i < C; ++i) { b[i] = smPi[i] * __bfloat162float(bx[n][i]); s += b[i]; }
        float inv = 1.f / s;
        #pragma unroll
        for (int i = 0; i < C; ++i) beta[n][i] = b[i] * inv;
    }
    __syncthreads();

    // ---- upward pass (leaves -> roots) ----
    for (int l = DEPTH; l >= 1; --l) {
        const int P = 1 << (l - 1);
        const int basep = P - 1;
        // t_beta[p,i] = 0.5 * sum_j A[i,j] * (beta[left,j] + beta[right,j])
        for (int it = tid; it < P * C; it += NTHREADS) {
            int pr = it >> 3, i = it & 7;
            int p = basep + pr;
            int cl = 2 * p + 1;
            float tb = 0.f;
            #pragma unroll
            for (int j = 0; j < C; ++j)
                tb += smA[i][j] * (beta[cl][j] + beta[cl + 1][j]);
            tbeta[p][i] = 0.5f * tb;
        }
        __syncthreads();
        // beta[p] = normalize(t_beta[p] * bx[p])
        for (int pr = tid; pr < P; pr += NTHREADS) {
            int p = basep + pr;
            float t[C], s = 0.f;
            #pragma unroll
            for (int i = 0; i < C; ++i) {
                t[i] = tbeta[p][i] * __bfloat162float(bx[p][i]);
                s += t[i];
            }
            float inv = 1.f / s;
            #pragma unroll
            for (int i = 0; i < C; ++i) beta[p][i] = t[i] * inv;
        }
        __syncthreads();
    }

    float acc = 0.f;
    // root B-term: eps[root] = beta[root]
    if (tid < C) acc += beta[0][tid] * __logf(__bfloat162float(bx[0][tid]));

    // ---- downward pass (roots -> leaves), eps overwrites beta in place ----
    for (int l = 1; l <= DEPTH; ++l) {
        const int P = 1 << (l - 1);
        const int basep = P - 1;
        const int basec = 2 * P - 1;
        // w[p,i] = eps[p,i] / t_beta[p,i]  (in place over tbeta)
        for (int it = tid; it < P * C; it += NTHREADS) {
            int pr = it >> 3, i = it & 7;
            int p = basep + pr;
            tbeta[p][i] = beta[p][i] / tbeta[p][i];
        }
        __syncthreads();
        const bool leaf = (l == DEPTH);
        for (int it = tid; it < 2 * P * C; it += NTHREADS) {
            int cr = it >> 3, j = it & 7;
            int ch = basec + cr;
            int p  = basep + (cr >> 1);
            float es = 0.f, ts = 0.f;
            #pragma unroll
            for (int i = 0; i < C; ++i) {
                float w = tbeta[p][i];
                es += w * smA[i][j];     // -> eps[ch,j] factor
                ts += w * AlogA[i][j];   // -> t_eps * logA contribution
            }
            float br = beta[ch][j];
            float ev = br * es;                                   // eps[ch,j]
            acc += 0.5f * br * ts + ev * __logf(__bfloat162float(bx[ch][j]));
            if (leaf) acc += ev * logPi[j];
            beta[ch][j] = ev;                                     // eps in place
        }
        __syncthreads();
    }

    // ---- block reduction of lik, out = -ll ----
    #pragma unroll
    for (int off = 32; off >= 1; off >>= 1)
        acc += __shfl_down(acc, off);
    if ((tid & 63) == 0) red[tid >> 6] = acc;
    __syncthreads();
    if (tid == 0)
        out[tree * G + g] = -(red[0] + red[1] + red[2] + red[3]);
}
} // namespace

extern "C" void kernel_launch(void* const* d_in, const int* in_sizes, int n_in,
                              void* d_out, int out_size, void* d_ws, size_t ws_size,
                              hipStream_t stream) {
    const float* A  = (const float*)d_in[0];
    const float* Bm = (const float*)d_in[1];
    const float* Pi = (const float*)d_in[2];
    const int*   x  = (const int*)d_in[3];
    float* out = (float*)d_out;
    hipLaunchKernelGGL(htmm_fused, dim3(64 * 8), dim3(NTHREADS), 0, stream,
                       A, Bm, Pi, x, out);
}

// Round 3
// 76.021 us; speedup vs baseline: 1.1782x; 1.1782x over previous
//
#include <hip/hip_runtime.h>

#define NT 256

namespace {
constexpr int C = 8, G = 8, M = 256, NPT = 1023, NINT = 511;

__global__ __launch_bounds__(NT, 2)
void htmm_fused(const float* __restrict__ Ag, const float* __restrict__ Bg,
                const float* __restrict__ Pig, const int* __restrict__ xg,
                float* __restrict__ out)
{
    __shared__ int   xs[NPT + 1];
    __shared__ float smB[C][M + 1];     // softmax(B) for this head
    __shared__ float logB[C][M + 1];    // log softmax(B)
    __shared__ float beta[NPT][9];      // upward beliefs; becomes eps in place
    __shared__ float tbe[NINT][9];      // t_beta; becomes w = eps/t_beta in place
    __shared__ float smA_s[C][9];
    __shared__ float alA_s[C][9];       // smA * log(smA)
    __shared__ float pi_s[2][C];        // smPi, log smPi
    __shared__ float red[4];

    const int tid  = threadIdx.x;
    const int wv   = tid >> 6;
    const int lane = tid & 63;
    const int s    = lane >> 3;         // sub-tree slot within wave
    const int q    = lane & 7;          // state role (i upward, j downward)
    const int tree = blockIdx.x >> 3, g = blockIdx.x & 7;

    // ---------- P0: stage x, build softmax tables ----------
    for (int n = tid; n < NPT; n += NT) xs[n] = xg[tree * NPT + n];

    {   // B: wave wv handles rows 2wv, 2wv+1 (one per half-wave). raw in [-5,5]: no max-sub needed.
        const int i  = 2 * wv + (lane >> 5);
        const int c0 = lane & 31;
        float raw[8], ex[8], ssum = 0.f;
        #pragma unroll
        for (int t = 0; t < 8; ++t) {
            raw[t] = Bg[(i * M + c0 + 32 * t) * G + g];
            ex[t]  = __expf(raw[t]);
            ssum  += ex[t];
        }
        #pragma unroll
        for (int m = 1; m <= 16; m <<= 1) ssum += __shfl_xor(ssum, m);
        const float inv = 1.f / ssum, ls = __logf(ssum);
        #pragma unroll
        for (int t = 0; t < 8; ++t) {
            smB[i][c0 + 32 * t]  = ex[t] * inv;
            logB[i][c0 + 32 * t] = raw[t] - ls;
        }
    }
    if (wv == 0) {                      // A softmax over parent dim i; lane=(i,j)=(s,q)
        const float raw = Ag[(s * C + q) * G + g];
        float e = __expf(raw), S = e;
        #pragma unroll
        for (int m = 8; m <= 32; m <<= 1) S += __shfl_xor(S, m);   // sum over i
        const float v = e / S;
        smA_s[s][q] = v;
        alA_s[s][q] = v * (raw - __logf(S));
    } else if (wv == 1 && lane < C) {   // Pi softmax
        const float raw = Pig[lane * G + g];
        float e = __expf(raw), S = e;
        #pragma unroll
        for (int m = 1; m <= 4; m <<= 1) S += __shfl_xor(S, m);
        pi_s[0][lane] = e / S;
        pi_s[1][lane] = raw - __logf(S);
    }
    __syncthreads();

    // per-lane register copies of A row/col, AlogA col, Pi
    float Arow[8], Acol[8], ALc[8], piR[8];
    #pragma unroll
    for (int j = 0; j < 8; ++j) Arow[j] = smA_s[q][j];
    #pragma unroll
    for (int i = 0; i < 8; ++i) { Acol[i] = smA_s[i][q]; ALc[i] = alA_s[i][q]; piR[i] = pi_s[0][i]; }
    const float logPi_q = pi_s[1][q];

    float acc = 0.f;

    auto upstep = [&](int p) {          // lane role q = parent state i
        const int cl = 2 * p + 1;
        float tb = 0.f;
        #pragma unroll
        for (int j = 0; j < 8; ++j) tb += Arow[j] * (beta[cl][j] + beta[cl + 1][j]);
        tb *= 0.5f;
        tbe[p][q] = tb;
        float u = tb * smB[q][xs[p]];
        float S = u;
        #pragma unroll
        for (int m = 1; m <= 4; m <<= 1) S += __shfl_xor(S, m);    // sum over i-group
        beta[p][q] = u / S;
    };
    auto wstep = [&](int p) {           // w = eps / t_beta, in place
        tbe[p][q] = beta[p][q] / tbe[p][q];
    };
    auto dstep = [&](int ch, int p, bool leaf) {   // lane role q = child state j
        float es = 0.f, ts = 0.f;
        #pragma unroll
        for (int i = 0; i < 8; ++i) {
            const float w = tbe[p][i];
            es += w * Acol[i];
            ts += w * ALc[i];
        }
        const float br = beta[ch][q];
        const float ev = br * es;                  // eps[ch][q]
        acc += 0.5f * br * ts + ev * logB[q][xs[ch]];
        if (leaf) acc += ev * logPi_q;
        else      beta[ch][q] = ev;
    };

    // ---------- P1: bottom-up, 16 sub-trees per wave, barrier-free ----------
    #pragma unroll
    for (int g2 = 0; g2 < 2; ++g2) {
        const int k0 = 16 * wv + 8 * g2, k = k0 + s;
        {   // leaf init: lane-per-leaf over this group's 64 leaves
            const int n  = 511 + 8 * k0 + lane;
            const int xv = xs[n];
            float u[8], S = 0.f;
            #pragma unroll
            for (int i = 0; i < 8; ++i) { u[i] = piR[i] * smB[i][xv]; S += u[i]; }
            const float inv = 1.f / S;
            #pragma unroll
            for (int i = 0; i < 8; ++i) beta[n][i] = u[i] * inv;
        }
        __builtin_amdgcn_wave_barrier();
        #pragma unroll
        for (int m = 0; m < 4; ++m) upstep(255 + 4 * k + m);   // depth-8 parents
        __builtin_amdgcn_wave_barrier();
        #pragma unroll
        for (int m = 0; m < 2; ++m) upstep(127 + 2 * k + m);   // depth-7
        __builtin_amdgcn_wave_barrier();
        upstep(63 + k);                                        // depth-6 (sub-tree root)
        __builtin_amdgcn_wave_barrier();
    }
    __syncthreads();

    // ---------- P2: top of tree (63 nodes), wave 0 only, barrier-free ----------
    if (wv == 0) {
        for (int d = 5; d >= 0; --d) {               // upward, parent depth d
            const int Pd = 1 << d, base = Pd - 1;
            for (int r0 = 0; r0 < Pd; r0 += 8)
                if (r0 + s < Pd) upstep(base + r0 + s);
            __builtin_amdgcn_wave_barrier();
        }
        if (lane < 8) acc += beta[0][lane] * logB[lane][xs[0]];   // root B-term (eps=beta)
        for (int dc = 1; dc <= 6; ++dc) {            // downward, child depth dc
            const int Pp = 1 << (dc - 1), basep = Pp - 1, basec = 2 * Pp - 1, NC = 2 * Pp;
            for (int r0 = 0; r0 < Pp; r0 += 8)
                if (r0 + s < Pp) wstep(basep + r0 + s);
            __builtin_amdgcn_wave_barrier();
            for (int r0 = 0; r0 < NC; r0 += 8)
                if (r0 + s < NC) {
                    const int cr = r0 + s;
                    dstep(basec + cr, basep + (cr >> 1), false);
                }
            __builtin_amdgcn_wave_barrier();
        }
    }
    __syncthreads();

    // ---------- P3: downward sub-trees, barrier-free ----------
    #pragma unroll
    for (int g2 = 0; g2 < 2; ++g2) {
        const int k = 16 * wv + 8 * g2 + s;
        wstep(63 + k);
        __builtin_amdgcn_wave_barrier();
        #pragma unroll
        for (int m = 0; m < 2; ++m) dstep(127 + 2 * k + m, 63 + k, false);
        __builtin_amdgcn_wave_barrier();
        #pragma unroll
        for (int m = 0; m < 2; ++m) wstep(127 + 2 * k + m);
        __builtin_amdgcn_wave_barrier();
        #pragma unroll
        for (int m = 0; m < 4; ++m) dstep(255 + 4 * k + m, 127 + 2 * k + (m >> 1), false);
        __builtin_amdgcn_wave_barrier();
        #pragma unroll
        for (int m = 0; m < 4; ++m) wstep(255 + 4 * k + m);
        __builtin_amdgcn_wave_barrier();
        #pragma unroll
        for (int m = 0; m < 8; ++m) dstep(511 + 8 * k + m, 255 + 4 * k + (m >> 1), true);
    }

    // ---------- P4: reduce ----------
    #pragma unroll
    for (int m = 1; m <= 32; m <<= 1) acc += __shfl_xor(acc, m);
    if (lane == 0) red[wv] = acc;
    __syncthreads();
    if (tid == 0) out[blockIdx.x] = -(red[0] + red[1] + red[2] + red[3]);
}
} // namespace

extern "C" void kernel_launch(void* const* d_in, const int* in_sizes, int n_in,
                              void* d_out, int out_size, void* d_ws, size_t ws_size,
                              hipStream_t stream) {
    const float* A  = (const float*)d_in[0];
    const float* Bm = (const float*)d_in[1];
    const float* Pi = (const float*)d_in[2];
    const int*   x  = (const int*)d_in[3];
    float* o = (float*)d_out;
    hipLaunchKernelGGL(htmm_fused, dim3(64 * 8), dim3(NT), 0, stream,
                       A, Bm, Pi, x, o);
}

// Round 9
// 74.887 us; speedup vs baseline: 1.1961x; 1.0151x over previous
//
#include <hip/hip_runtime.h>

#define NT 256

namespace {
constexpr int C = 8, G = 8, M = 256, NPT = 1023;

__device__ __forceinline__ float rcpf(float x) { return __builtin_amdgcn_rcpf(x); }

__global__ __launch_bounds__(NT, 2)
void htmm_fused(const float* __restrict__ Ag, const float* __restrict__ Bg,
                const float* __restrict__ Pig, const int* __restrict__ xg,
                float* __restrict__ out)
{
    __shared__ int   xs[NPT + 1];
    __shared__ float smB[C][M + 1];     // softmax(B)
    __shared__ float logB[C][M + 1];    // log softmax(B)
    __shared__ float beta_t[127][9];    // top-of-tree beliefs (nodes 0..126); becomes eps in place
    __shared__ float tbe_t[63][9];      // top-of-tree t_beta (nodes 0..62); becomes w in place
    __shared__ float smA_s[C][9];
    __shared__ float alA_s[C][9];       // smA * log(smA)
    __shared__ float pi_s[2][C];        // smPi, log smPi
    __shared__ float red[4];

    const int tid  = threadIdx.x;
    const int wv   = tid >> 6;
    const int lane = tid & 63;
    const int s    = lane >> 3;         // slot (sub-tree lane-group) within wave
    const int q    = lane & 7;          // state role
    const int tree = blockIdx.x >> 3, g = blockIdx.x & 7;

    // ---------- P0: stage x, build softmax tables ----------
    for (int n = tid; n < NPT; n += NT) xs[n] = xg[tree * NPT + n];

    {   // B: wave wv handles rows 2wv, 2wv+1. raw in [-5,5]: no max-subtract needed.
        const int i  = 2 * wv + (lane >> 5);
        const int c0 = lane & 31;
        float raw[8], ex[8], ssum = 0.f;
        #pragma unroll
        for (int t = 0; t < 8; ++t) {
            raw[t] = Bg[(i * M + c0 + 32 * t) * G + g];
            ex[t]  = __expf(raw[t]);
            ssum  += ex[t];
        }
        #pragma unroll
        for (int m = 1; m <= 16; m <<= 1) ssum += __shfl_xor(ssum, m);
        const float inv = rcpf(ssum), ls = __logf(ssum);
        #pragma unroll
        for (int t = 0; t < 8; ++t) {
            smB[i][c0 + 32 * t]  = ex[t] * inv;
            logB[i][c0 + 32 * t] = raw[t] - ls;
        }
    }
    if (wv == 0) {                      // A softmax over parent dim i; lane=(i,j)=(s,q)
        const float raw = Ag[(s * C + q) * G + g];
        float e = __expf(raw), S = e;
        #pragma unroll
        for (int m = 8; m <= 32; m <<= 1) S += __shfl_xor(S, m);
        const float v = e / S;
        smA_s[s][q] = v;
        alA_s[s][q] = v * (raw - __logf(S));
    } else if (wv == 1 && lane < C) {   // Pi softmax
        const float raw = Pig[lane * G + g];
        float e = __expf(raw), S = e;
        #pragma unroll
        for (int m = 1; m <= 4; m <<= 1) S += __shfl_xor(S, m);
        pi_s[0][lane] = e / S;
        pi_s[1][lane] = raw - __logf(S);
    }
    __syncthreads();

    float Arow[8], Acol[8], ALc[8];
    #pragma unroll
    for (int j = 0; j < 8; ++j) Arow[j] = smA_s[q][j];
    #pragma unroll
    for (int i = 0; i < 8; ++i) { Acol[i] = smA_s[i][q]; ALc[i] = alA_s[i][q]; }
    const float pi_q = pi_s[0][q], logPi_q = pi_s[1][q];

    float acc = 0.f;

    // ---------- P1: bottom-up sub-trees, register-resident, shuffle-based ----------
    // slot s owns sub-trees k = 16wv+s and 16wv+8+s (roots 63+k at depth 6)
    float b9[2][8], tb8[2][4], b8[2][4], tb7[2][2], b7[2][2], tb6[2];
    #pragma unroll
    for (int h = 0; h < 2; ++h) {
        const int k = 16 * wv + 8 * h + s;
        #pragma unroll
        for (int m = 0; m < 8; ++m) {   // leaves 511+8k+m
            float u = pi_q * smB[q][xs[511 + 8 * k + m]];
            float S = u;
            S += __shfl_xor(S, 1); S += __shfl_xor(S, 2); S += __shfl_xor(S, 4);
            b9[h][m] = u * rcpf(S);
        }
        #pragma unroll
        for (int m = 0; m < 4; ++m) {   // depth-8 parents 255+4k+m
            float c = b9[h][2 * m] + b9[h][2 * m + 1];
            float tb = 0.f;
            #pragma unroll
            for (int j = 0; j < 8; ++j) tb += Arow[j] * __shfl(c, j, 8);
            tb *= 0.5f; tb8[h][m] = tb;
            float u = tb * smB[q][xs[255 + 4 * k + m]];
            float S = u;
            S += __shfl_xor(S, 1); S += __shfl_xor(S, 2); S += __shfl_xor(S, 4);
            b8[h][m] = u * rcpf(S);
        }
        #pragma unroll
        for (int m = 0; m < 2; ++m) {   // depth-7 parents 127+2k+m
            float c = b8[h][2 * m] + b8[h][2 * m + 1];
            float tb = 0.f;
            #pragma unroll
            for (int j = 0; j < 8; ++j) tb += Arow[j] * __shfl(c, j, 8);
            tb *= 0.5f; tb7[h][m] = tb;
            float u = tb * smB[q][xs[127 + 2 * k + m]];
            float S = u;
            S += __shfl_xor(S, 1); S += __shfl_xor(S, 2); S += __shfl_xor(S, 4);
            b7[h][m] = u * rcpf(S);
        }
        {                               // depth-6 root 63+k
            float c = b7[h][0] + b7[h][1];
            float tb = 0.f;
            #pragma unroll
            for (int j = 0; j < 8; ++j) tb += Arow[j] * __shfl(c, j, 8);
            tb *= 0.5f; tb6[h] = tb;
            float u = tb * smB[q][xs[63 + k]];
            float S = u;
            S += __shfl_xor(S, 1); S += __shfl_xor(S, 2); S += __shfl_xor(S, 4);
            beta_t[63 + k][q] = u * rcpf(S);
        }
    }
    __syncthreads();

    // ---------- P2: top of tree (63 nodes), wave 0 only ----------
    if (wv == 0) {
        for (int d = 5; d >= 0; --d) {               // upward
            const int Pd = 1 << d, base = Pd - 1;
            for (int r0 = 0; r0 < Pd; r0 += 8)
                if (r0 + s < Pd) {
                    const int p = base + r0 + s, cl = 2 * p + 1;
                    float tb = 0.f;
                    #pragma unroll
                    for (int j = 0; j < 8; ++j) tb += Arow[j] * (beta_t[cl][j] + beta_t[cl + 1][j]);
                    tb *= 0.5f; tbe_t[p][q] = tb;
                    float u = tb * smB[q][xs[p]];
                    float S = u;
                    S += __shfl_xor(S, 1); S += __shfl_xor(S, 2); S += __shfl_xor(S, 4);
                    beta_t[p][q] = u * rcpf(S);
                }
            __builtin_amdgcn_wave_barrier();
        }
        if (lane < 8) acc += beta_t[0][lane] * logB[lane][xs[0]];   // root B-term
        for (int dc = 1; dc <= 6; ++dc) {            // downward
            const int Pp = 1 << (dc - 1), basep = Pp - 1, basec = 2 * Pp - 1, NCc = 2 * Pp;
            for (int r0 = 0; r0 < Pp; r0 += 8)
                if (r0 + s < Pp) {
                    const int p = basep + r0 + s;
                    tbe_t[p][q] = beta_t[p][q] * rcpf(tbe_t[p][q]);   // w in place
                }
            __builtin_amdgcn_wave_barrier();
            for (int r0 = 0; r0 < NCc; r0 += 8)
                if (r0 + s < NCc) {
                    const int cr = r0 + s, ch = basec + cr, p = basep + (cr >> 1);
                    float es = 0.f, ts = 0.f;
                    #pragma unroll
                    for (int i = 0; i < 8; ++i) {
                        const float w = tbe_t[p][i];
                        es += w * Acol[i]; ts += w * ALc[i];
                    }
                    const float br = beta_t[ch][q];
                    const float ev = br * es;
                    acc += 0.5f * br * ts + ev * logB[q][xs[ch]];
                    beta_t[ch][q] = ev;              // eps in place (incl. depth-6 roots)
                }
            __builtin_amdgcn_wave_barrier();
        }
    }
    __syncthreads();

    // ---------- P3: downward sub-trees, register-resident, shuffle-based ----------
    #pragma unroll
    for (int h = 0; h < 2; ++h) {
        const int k = 16 * wv + 8 * h + s;
        const float w6 = beta_t[63 + k][q] * rcpf(tb6[h]);
        float w7[2], w8[4];
        #pragma unroll
        for (int m = 0; m < 2; ++m) {   // depth-7 children
            float es = 0.f, ts = 0.f;
            #pragma unroll
            for (int i = 0; i < 8; ++i) {
                const float wi = __shfl(w6, i, 8);
                es += wi * Acol[i]; ts += wi * ALc[i];
            }
            const float br = b7[h][m];
            const float ev = br * es;
            acc += 0.5f * br * ts + ev * logB[q][xs[127 + 2 * k + m]];
            w7[m] = ev * rcpf(tb7[h][m]);
        }
        #pragma unroll
        for (int m = 0; m < 4; ++m) {   // depth-8 children
            const float wp = w7[m >> 1];
            float es = 0.f, ts = 0.f;
            #pragma unroll
            for (int i = 0; i < 8; ++i) {
                const float wi = __shfl(wp, i, 8);
                es += wi * Acol[i]; ts += wi * ALc[i];
            }
            const float br = b8[h][m];
            const float ev = br * es;
            acc += 0.5f * br * ts + ev * logB[q][xs[255 + 4 * k + m]];
            w8[m] = ev * rcpf(tb8[h][m]);
        }
        #pragma unroll
        for (int m = 0; m < 8; ++m) {   // leaves
            const float wp = w8[m >> 1];
            float es = 0.f, ts = 0.f;
            #pragma unroll
            for (int i = 0; i < 8; ++i) {
                const float wi = __shfl(wp, i, 8);
                es += wi * Acol[i]; ts += wi * ALc[i];
            }
            const float br = b9[h][m];
            const float ev = br * es;
            acc += 0.5f * br * ts + ev * (logB[q][xs[511 + 8 * k + m]] + logPi_q);
        }
    }

    // ---------- P4: reduce ----------
    #pragma unroll
    for (int m = 1; m <= 32; m <<= 1) acc += __shfl_xor(acc, m);
    if (lane == 0) red[wv] = acc;
    __syncthreads();
    if (tid == 0) out[blockIdx.x] = -(red[0] + red[1] + red[2] + red[3]);
}
} // namespace

extern "C" void kernel_launch(void* const* d_in, const int* in_sizes, int n_in,
                              void* d_out, int out_size, void* d_ws, size_t ws_size,
                              hipStream_t stream) {
    const float* A  = (const float*)d_in[0];
    const float* Bm = (const float*)d_in[1];
    const float* Pi = (const float*)d_in[2];
    const int*   x  = (const int*)d_in[3];
    float* o = (float*)d_out;
    hipLaunchKernelGGL(htmm_fused, dim3(64 * 8), dim3(NT), 0, stream,
                       A, Bm, Pi, x, o);
}